// Round 3
// baseline (112.141 us; speedup 1.0000x reference)
//
#include <hip/hip_runtime.h>
#include <math.h>

#define TEMP_F 0.07f
#define NCON 20
#define LDIM 512
#define NROWS 32768
#define NSEL 16384
#define NBLK 1024

// ws layout (floats): [0 .. NBLK) block partial sums of "term"
// total loss = (sum over all 32768 selections of term) / 16384
//   term_i = log(den_i) - dot(h_norm[r], ebar_b)/TEMP
// (branch means are both over 16384 and are summed, so a single global
//  sum / 16384 is exact.)

__global__ __launch_bounds__(256) void fused_kernel(const float* __restrict__ hg,
                                                    const float* __restrict__ sim,
                                                    const float* __restrict__ all_emb,
                                                    const int* __restrict__ sz_idx,
                                                    const int* __restrict__ nsz_idx,
                                                    const int* __restrict__ Psz,
                                                    const int* __restrict__ Pnsz,
                                                    float* __restrict__ ws) {
    __shared__ float ebs[LDIM];   // ebar seizure
    __shared__ float ebn[LDIM];   // ebar non-seizure
    __shared__ float red[4];
    const int t = threadIdx.x;

    // Per-block e_bar build from all_emb (40 KB, L2-resident; 1024 blocks
    // re-reading it ~20 MB of L2 traffic, ~1 us total). Duplicates in P idx
    // are counted in the mean (matches ref's all_emb[P_idx].mean(0)).
    for (int j = t; j < LDIM; j += 256) {
        float s1 = 0.f, s2 = 0.f;
#pragma unroll
        for (int k = 0; k < 5; ++k) {
            s1 += all_emb[Psz[k]  * LDIM + j];
            s2 += all_emb[Pnsz[k] * LDIM + j];
        }
        ebs[j] = s1 * 0.2f;
        ebn[j] = s2 * 0.2f;
    }
    // keep-masks (duplicates idempotent — matches at[P].set(0))
    unsigned msz = (1u << NCON) - 1u, mnsz = (1u << NCON) - 1u;
#pragma unroll
    for (int k = 0; k < 5; ++k) { msz &= ~(1u << Psz[k]); mnsz &= ~(1u << Pnsz[k]); }
    __syncthreads();

    const int lane = t & 63;
    const int w    = t >> 6;

    // this lane's 8-float slice of each ebar
    const float4 es0 = ((const float4*)ebs)[lane * 2];
    const float4 es1 = ((const float4*)ebs)[lane * 2 + 1];
    const float4 en0 = ((const float4*)ebn)[lane * 2];
    const float4 en1 = ((const float4*)ebn)[lane * 2 + 1];

    const float invT = 1.0f / TEMP_F;
    const int gwave  = blockIdx.x * 4 + w;   // global wave id, < 4096
    const int nwaves = NBLK * 4;

    float acc = 0.f;  // identical across lanes after reductions

    for (int i = gwave; i < 2 * NSEL; i += nwaves) {
        const int b = i >> 14;               // 0: seizure branch, 1: non-seizure
        const int r = (b == 0) ? sz_idx[i] : nsz_idx[i - NSEL];

        // gather hg row r: 2 KB contiguous, 8 floats/lane
        const float4* rp = (const float4*)hg + (size_t)r * (LDIM / 4) + lane * 2;
        const float4 a0 = rp[0];
        const float4 a1 = rp[1];

        const float4 b0 = (b == 0) ? es0 : en0;
        const float4 b1 = (b == 0) ? es1 : en1;
        const unsigned mask = (b == 0) ? msz : mnsz;

        float ss  = a0.x*a0.x + a0.y*a0.y + a0.z*a0.z + a0.w*a0.w
                  + a1.x*a1.x + a1.y*a1.y + a1.z*a1.z + a1.w*a1.w;
        float dot = a0.x*b0.x + a0.y*b0.y + a0.z*b0.z + a0.w*b0.w
                  + a1.x*b1.x + a1.y*b1.y + a1.z*b1.z + a1.w*b1.w;

        // denominator: lanes 0..19 each hold one sim value
        float den = 0.f;
        if (lane < NCON && (mask & (1u << lane)))
            den = __builtin_expf(sim[(size_t)r * NCON + lane] * invT);

#pragma unroll
        for (int off = 32; off; off >>= 1) {
            ss  += __shfl_xor(ss,  off);
            dot += __shfl_xor(dot, off);
            den += __shfl_xor(den, off);
        }
        acc += __builtin_logf(den) - dot * invT / fmaxf(__builtin_sqrtf(ss), 1e-12f);
    }

    // block reduction of acc (all lanes of a wave hold the same value)
    if (lane == 0) red[w] = acc;
    __syncthreads();
    if (t == 0) ws[blockIdx.x] = red[0] + red[1] + red[2] + red[3];
}

__global__ __launch_bounds__(256) void finish_kernel(const float* __restrict__ ws,
                                                     float* __restrict__ out) {
    __shared__ float red[4];
    const int t = threadIdx.x;
    float s = ws[t] + ws[t + 256] + ws[t + 512] + ws[t + 768];
#pragma unroll
    for (int off = 32; off; off >>= 1) s += __shfl_xor(s, off);
    const int lane = t & 63, w = t >> 6;
    if (lane == 0) red[w] = s;
    __syncthreads();
    if (t == 0) out[0] = (red[0] + red[1] + red[2] + red[3]) * (1.0f / NSEL);
}

extern "C" void kernel_launch(void* const* d_in, const int* in_sizes, int n_in,
                              void* d_out, int out_size, void* d_ws, size_t ws_size,
                              hipStream_t stream) {
    const float* hg       = (const float*)d_in[0];
    const float* hg_corr  = (const float*)d_in[1];
    const float* all_emb  = (const float*)d_in[2];
    const int*   sz_idx   = (const int*)d_in[3];
    const int*   nsz_idx  = (const int*)d_in[4];
    const int*   Psz      = (const int*)d_in[5];
    const int*   Pnsz     = (const int*)d_in[6];
    float* out = (float*)d_out;
    float* ws  = (float*)d_ws;

    fused_kernel<<<NBLK, 256, 0, stream>>>(hg, hg_corr, all_emb,
                                           sz_idx, nsz_idx, Psz, Pnsz, ws);
    finish_kernel<<<1, 256, 0, stream>>>(ws, out);
}